// Round 1
// baseline (3470.750 us; speedup 1.0000x reference)
//
#include <hip/hip_runtime.h>
#include <math.h>

#define NROWS 131072
#define DIM   64
#define KCENT 1024
#define DECAY 0.99f
#define EPS_  1e-5f

// ---------------- ws layout (float elements) ----------------
// csum   [K*D]  @ 0        (zeroed)
// counts [K]    @ 65536    (zeroed)
// c_sq   [K]    @ 66560
// cs     [K]    @ 67584
// cnewT  [K*D]  @ 68608    ([K][D], transposed codebook for coalesced gather)
// ind    [N]    @ 134144   (int)
// total ~1.04 MB

// ---------- K1: ||c_k||^2 ----------
__global__ void k_csq(const float* __restrict__ cent, float* __restrict__ c_sq) {
    int k = blockIdx.x * blockDim.x + threadIdx.x;   // 0..1023
    float s = 0.f;
#pragma unroll
    for (int d = 0; d < DIM; ++d) {
        float v = cent[d * KCENT + k];               // coalesced across lanes
        s = fmaf(v, v, s);
    }
    c_sq[k] = s;
}

// ---------- K2: nearest-centroid assignment + segment-sum scatter ----------
#define CHUNK 128
#define LSTR  68   // 64 + 4 pad: keeps 16B alignment, breaks bank conflicts to 8-way

__global__ __launch_bounds__(256) void k_assign(
    const float* __restrict__ x, const float* __restrict__ cent,
    const float* __restrict__ c_sq, int* __restrict__ ind,
    float* __restrict__ counts, float* __restrict__ csum) {
    __shared__ float ctile[CHUNK * LSTR];
    __shared__ float c2s[CHUNK];

    const int n = blockIdx.x * 256 + threadIdx.x;
    float4 xv[16];
    const float4* xr = (const float4*)(x + (size_t)n * DIM);
#pragma unroll
    for (int i = 0; i < 16; ++i) xv[i] = xr[i];

    float best = 3.402823466e38f;
    int   bi   = 0;

    for (int k0 = 0; k0 < KCENT; k0 += CHUNK) {
        __syncthreads();
        // stage CHUNK centroids, transposed to [kk][d]
#pragma unroll
        for (int it = 0; it < (CHUNK * DIM) / 256; ++it) {
            int t  = threadIdx.x + it * 256;
            int kk = t & (CHUNK - 1);
            int d  = t >> 7;
            ctile[kk * LSTR + d] = cent[d * KCENT + k0 + kk];  // coalesced global read
        }
        if (threadIdx.x < CHUNK) c2s[threadIdx.x] = c_sq[k0 + threadIdx.x];
        __syncthreads();

        for (int kk = 0; kk < CHUNK; ++kk) {
            const float4* cv = (const float4*)(ctile + kk * LSTR);  // wave-uniform -> broadcast
            float4 a = make_float4(0.f, 0.f, 0.f, 0.f);
#pragma unroll
            for (int i = 0; i < 16; ++i) {
                float4 c = cv[i];
                a.x = fmaf(xv[i].x, c.x, a.x);
                a.y = fmaf(xv[i].y, c.y, a.y);
                a.z = fmaf(xv[i].z, c.z, a.z);
                a.w = fmaf(xv[i].w, c.w, a.w);
            }
            float dot  = (a.x + a.y) + (a.z + a.w);
            float dist = c2s[kk] - 2.0f * dot;   // x_sq omitted: row-constant
            if (dist < best) { best = dist; bi = k0 + kk; }  // strict < == first-min tiebreak
        }
    }

    ind[n] = bi;
    atomicAdd(&counts[bi], 1.0f);
    float* dst = csum + (size_t)bi * DIM;
#pragma unroll
    for (int i = 0; i < 16; ++i) {
        atomicAdd(dst + 4 * i + 0, xv[i].x);
        atomicAdd(dst + 4 * i + 1, xv[i].y);
        atomicAdd(dst + 4 * i + 2, xv[i].z);
        atomicAdd(dst + 4 * i + 3, xv[i].w);
    }
}

// ---------- K3a: EMA cluster sizes, Laplace smoothing -> cs[k] ----------
__global__ void k_stats(const float* __restrict__ cluster_size,
                        const float* __restrict__ counts,
                        float* __restrict__ cs) {
    __shared__ float red[KCENT];
    int k = threadIdx.x;
    float cls = DECAY * cluster_size[k] + (1.0f - DECAY) * counts[k];
    red[k] = cls;
    __syncthreads();
    for (int off = KCENT / 2; off > 0; off >>= 1) {
        if (k < off) red[k] += red[k + off];
        __syncthreads();
    }
    float ntot = red[0];
    cs[k] = (cls + EPS_) / (ntot + KCENT * EPS_) * ntot;
}

// ---------- K3b: centroids_new, stored transposed [K][D] ----------
__global__ void k_newcent(const float* __restrict__ avg,
                          const float* __restrict__ csum,
                          const float* __restrict__ cs,
                          float* __restrict__ cnewT) {
    int idx = blockIdx.x * blockDim.x + threadIdx.x;  // = k*64 + d
    int k = idx >> 6, d = idx & 63;
    float v = DECAY * avg[d * KCENT + k] + (1.0f - DECAY) * csum[idx];
    cnewT[idx] = v / cs[k];
}

// ---------- K4: gather quantized rows + MSE loss ----------
__global__ __launch_bounds__(256) void k_out(
    const float* __restrict__ x, const int* __restrict__ ind,
    const float* __restrict__ cnewT, float* __restrict__ out,
    float* __restrict__ loss) {
    const int tid = threadIdx.x;
    const int row = blockIdx.x * 16 + (tid >> 4);  // 16 rows/block, 16 lanes/row
    const int l16 = tid & 15;

    int k = ind[row];
    float4 q  = ((const float4*)(cnewT + (size_t)k * DIM))[l16];
    float4 xw = ((const float4*)(x + (size_t)row * DIM))[l16];
    ((float4*)(out + (size_t)row * DIM))[l16] = q;

    float dx = xw.x - q.x, dy = xw.y - q.y, dz = xw.z - q.z, dw = xw.w - q.w;
    float p = dx * dx + dy * dy + dz * dz + dw * dw;

    __shared__ float red[256];
    red[tid] = p;
    __syncthreads();
    for (int off = 128; off > 0; off >>= 1) {
        if (tid < off) red[tid] += red[tid + off];
        __syncthreads();
    }
    if (tid == 0)
        atomicAdd(loss, red[0] * (1.0f / ((float)NROWS * (float)DIM)));
}

extern "C" void kernel_launch(void* const* d_in, const int* in_sizes, int n_in,
                              void* d_out, int out_size, void* d_ws, size_t ws_size,
                              hipStream_t stream) {
    const float* x            = (const float*)d_in[0];
    const float* cent         = (const float*)d_in[1];
    const float* cluster_size = (const float*)d_in[2];
    const float* avg          = (const float*)d_in[3];
    float* out = (float*)d_out;

    float* ws     = (float*)d_ws;
    float* csum   = ws;                   // K*D
    float* counts = ws + 65536;           // K
    float* c_sq   = ws + 66560;           // K
    float* cs     = ws + 67584;           // K
    float* cnewT  = ws + 68608;           // K*D
    int*   ind    = (int*)(ws + 134144);  // N

    // zero accumulators (csum + counts are adjacent) and the loss slot
    hipMemsetAsync(csum, 0, (65536 + 1024) * sizeof(float), stream);
    hipMemsetAsync(out + (size_t)NROWS * DIM, 0, sizeof(float), stream);

    k_csq<<<KCENT / 256, 256, 0, stream>>>(cent, c_sq);
    k_assign<<<NROWS / 256, 256, 0, stream>>>(x, cent, c_sq, ind, counts, csum);
    k_stats<<<1, KCENT, 0, stream>>>(cluster_size, counts, cs);
    k_newcent<<<(KCENT * DIM) / 256, 256, 0, stream>>>(avg, csum, cs, cnewT);
    k_out<<<NROWS / 16, 256, 0, stream>>>(x, ind, cnewT, out,
                                          out + (size_t)NROWS * DIM);
}

// Round 2
// 1185.603 us; speedup vs baseline: 2.9274x; 2.9274x over previous
//
#include <hip/hip_runtime.h>
#include <math.h>

#define NROWS 131072
#define DIM   64
#define KCENT 1024
#define DECAY 0.99f
#define EPS_  1e-5f

// ---------------- ws layout (float elements) ----------------
// csum   [K*D]  @ 0        (written densely by k_segsum — no zeroing needed)
// cnt    [K]    @ 65536    (int, zeroed)
// c_sq   [K]    @ 66560
// cs     [K]    @ 67584
// cnewT  [K*D]  @ 68608    ([K][D] codebook for coalesced gather)
// ind    [N]    @ 134144   (int)
// perm   [N]    @ 265216   (int, rows sorted by cluster)
// start  [K]    @ 396288   (int)
// cursor [K]    @ 397312   (int)
// total ~1.56 MB

// ---------- K1: ||c_k||^2 ----------
__global__ void k_csq(const float* __restrict__ cent, float* __restrict__ c_sq) {
    int k = blockIdx.x * blockDim.x + threadIdx.x;   // 0..1023
    float s = 0.f;
#pragma unroll
    for (int d = 0; d < DIM; ++d) {
        float v = cent[d * KCENT + k];               // coalesced across lanes
        s = fmaf(v, v, s);
    }
    c_sq[k] = s;
}

// ---------- K2: nearest-centroid assignment (no per-dim atomics) ----------
#define CHUNK 128
#define LSTR  68   // 64 + 4 pad: keeps 16B alignment, breaks bank conflicts

__global__ __launch_bounds__(256) void k_assign(
    const float* __restrict__ x, const float* __restrict__ cent,
    const float* __restrict__ c_sq, int* __restrict__ ind,
    int* __restrict__ cnt) {
    __shared__ float ctile[CHUNK * LSTR];
    __shared__ float c2s[CHUNK];
    __shared__ int   hist[KCENT];

    // zero block-local histogram
#pragma unroll
    for (int i = 0; i < KCENT / 256; ++i) hist[threadIdx.x + i * 256] = 0;

    const int n = blockIdx.x * 256 + threadIdx.x;
    float4 xv[16];
    const float4* xr = (const float4*)(x + (size_t)n * DIM);
#pragma unroll
    for (int i = 0; i < 16; ++i) xv[i] = xr[i];

    float best = 3.402823466e38f;
    int   bi   = 0;

    for (int k0 = 0; k0 < KCENT; k0 += CHUNK) {
        __syncthreads();   // also orders hist-zeroing before the atomics below
        // stage CHUNK centroids, transposed to [kk][d]
#pragma unroll
        for (int it = 0; it < (CHUNK * DIM) / 256; ++it) {
            int t  = threadIdx.x + it * 256;
            int kk = t & (CHUNK - 1);
            int d  = t >> 7;
            ctile[kk * LSTR + d] = cent[d * KCENT + k0 + kk];  // coalesced global read
        }
        if (threadIdx.x < CHUNK) c2s[threadIdx.x] = c_sq[k0 + threadIdx.x];
        __syncthreads();

        for (int kk = 0; kk < CHUNK; ++kk) {
            const float4* cv = (const float4*)(ctile + kk * LSTR);  // wave-uniform -> broadcast
            float4 a = make_float4(0.f, 0.f, 0.f, 0.f);
#pragma unroll
            for (int i = 0; i < 16; ++i) {
                float4 c = cv[i];
                a.x = fmaf(xv[i].x, c.x, a.x);
                a.y = fmaf(xv[i].y, c.y, a.y);
                a.z = fmaf(xv[i].z, c.z, a.z);
                a.w = fmaf(xv[i].w, c.w, a.w);
            }
            float dot  = (a.x + a.y) + (a.z + a.w);
            float dist = c2s[kk] - 2.0f * dot;   // x_sq omitted: row-constant
            if (dist < best) { best = dist; bi = k0 + kk; }  // strict < == first-min
        }
    }

    ind[n] = bi;
    atomicAdd(&hist[bi], 1);          // LDS atomic — cheap
    __syncthreads();
#pragma unroll
    for (int i = 0; i < KCENT / 256; ++i) {
        int b = threadIdx.x + i * 256;
        int v = hist[b];
        if (v) atomicAdd(&cnt[b], v); // ~226 global atomics / block
    }
}

// ---------- K3: EMA stats + Laplace cs + exclusive prefix sum ----------
__global__ void k_scan(const float* __restrict__ cluster_size,
                       const int* __restrict__ cnt,
                       float* __restrict__ cs,
                       int* __restrict__ start, int* __restrict__ cursor) {
    __shared__ int   sa[KCENT], sb[KCENT];
    __shared__ float rf[KCENT];
    const int t = threadIdx.x;
    const int c = cnt[t];

    // EMA cluster size + total + Laplace smoothing
    float cls = DECAY * cluster_size[t] + (1.0f - DECAY) * (float)c;
    rf[t] = cls;
    __syncthreads();
    for (int off = KCENT / 2; off > 0; off >>= 1) {
        if (t < off) rf[t] += rf[t + off];
        __syncthreads();
    }
    float ntot = rf[0];
    cs[t] = (cls + EPS_) / (ntot + KCENT * EPS_) * ntot;

    // exclusive prefix sum of counts (Hillis-Steele, double buffer)
    sa[t] = c;
    __syncthreads();
    int* pin = sa; int* pout = sb;
    for (int off = 1; off < KCENT; off <<= 1) {
        pout[t] = pin[t] + ((t >= off) ? pin[t - off] : 0);
        __syncthreads();
        int* tmp = pin; pin = pout; pout = tmp;
    }
    int excl = pin[t] - c;
    start[t]  = excl;
    cursor[t] = excl;
}

// ---------- K4: scatter rows into cluster-sorted order ----------
__global__ __launch_bounds__(256) void k_scatter(
    const int* __restrict__ ind, int* __restrict__ cursor,
    int* __restrict__ perm) {
    int n = blockIdx.x * 256 + threadIdx.x;
    int bi = ind[n];
    int pos = atomicAdd(&cursor[bi], 1);   // 131K atomics on 1024 addrs
    perm[pos] = n;
}

// ---------- K5: dense per-cluster segment sum (no atomics) ----------
__global__ __launch_bounds__(256) void k_segsum(
    const float* __restrict__ x, const int* __restrict__ perm,
    const int* __restrict__ start, const int* __restrict__ cnt,
    float* __restrict__ csum) {
    const int k = blockIdx.x;
    const int w = threadIdx.x >> 6;    // wave 0..3
    const int d = threadIdx.x & 63;    // dim
    const int s = start[k];
    const int c = cnt[k];

    float acc = 0.f;
    int r = w;
    for (; r + 4 < c; r += 8) {        // 2 rows in flight per iter
        int row0 = perm[s + r];
        int row1 = perm[s + r + 4];
        acc += x[(size_t)row0 * DIM + d];
        acc += x[(size_t)row1 * DIM + d];
    }
    for (; r < c; r += 4)
        acc += x[(size_t)perm[s + r] * DIM + d];

    __shared__ float red[256];
    red[threadIdx.x] = acc;
    __syncthreads();
    if (w == 0)
        csum[(size_t)k * DIM + d] = red[d] + red[64 + d] + red[128 + d] + red[192 + d];
}

// ---------- K6: centroids_new, stored transposed [K][D] ----------
__global__ void k_newcent(const float* __restrict__ avg,
                          const float* __restrict__ csum,
                          const float* __restrict__ cs,
                          float* __restrict__ cnewT) {
    int idx = blockIdx.x * blockDim.x + threadIdx.x;  // = k*64 + d
    int k = idx >> 6, d = idx & 63;
    float v = DECAY * avg[d * KCENT + k] + (1.0f - DECAY) * csum[idx];
    cnewT[idx] = v / cs[k];
}

// ---------- K7: gather quantized rows + MSE loss ----------
__global__ __launch_bounds__(256) void k_out(
    const float* __restrict__ x, const int* __restrict__ ind,
    const float* __restrict__ cnewT, float* __restrict__ out,
    float* __restrict__ loss) {
    const int tid = threadIdx.x;
    const int row = blockIdx.x * 16 + (tid >> 4);  // 16 rows/block, 16 lanes/row
    const int l16 = tid & 15;

    int k = ind[row];
    float4 q  = ((const float4*)(cnewT + (size_t)k * DIM))[l16];
    float4 xw = ((const float4*)(x + (size_t)row * DIM))[l16];
    ((float4*)(out + (size_t)row * DIM))[l16] = q;

    float dx = xw.x - q.x, dy = xw.y - q.y, dz = xw.z - q.z, dw = xw.w - q.w;
    float p = dx * dx + dy * dy + dz * dz + dw * dw;

    __shared__ float red[256];
    red[tid] = p;
    __syncthreads();
    for (int off = 128; off > 0; off >>= 1) {
        if (tid < off) red[tid] += red[tid + off];
        __syncthreads();
    }
    if (tid == 0)
        atomicAdd(loss, red[0] * (1.0f / ((float)NROWS * (float)DIM)));
}

extern "C" void kernel_launch(void* const* d_in, const int* in_sizes, int n_in,
                              void* d_out, int out_size, void* d_ws, size_t ws_size,
                              hipStream_t stream) {
    const float* x            = (const float*)d_in[0];
    const float* cent         = (const float*)d_in[1];
    const float* cluster_size = (const float*)d_in[2];
    const float* avg          = (const float*)d_in[3];
    float* out = (float*)d_out;

    float* ws     = (float*)d_ws;
    float* csum   = ws;                    // K*D
    int*   cnt    = (int*)(ws + 65536);    // K
    float* c_sq   = ws + 66560;            // K
    float* cs     = ws + 67584;            // K
    float* cnewT  = ws + 68608;            // K*D
    int*   ind    = (int*)(ws + 134144);   // N
    int*   perm   = (int*)(ws + 265216);   // N
    int*   start  = (int*)(ws + 396288);   // K
    int*   cursor = (int*)(ws + 397312);   // K

    hipMemsetAsync(cnt, 0, KCENT * sizeof(int), stream);
    hipMemsetAsync(out + (size_t)NROWS * DIM, 0, sizeof(float), stream);  // loss slot

    k_csq   <<<KCENT / 256, 256, 0, stream>>>(cent, c_sq);
    k_assign<<<NROWS / 256, 256, 0, stream>>>(x, cent, c_sq, ind, cnt);
    k_scan  <<<1, KCENT, 0, stream>>>(cluster_size, cnt, cs, start, cursor);
    k_scatter<<<NROWS / 256, 256, 0, stream>>>(ind, cursor, perm);
    k_segsum<<<KCENT, 256, 0, stream>>>(x, perm, start, cnt, csum);
    k_newcent<<<(KCENT * DIM) / 256, 256, 0, stream>>>(avg, csum, cs, cnewT);
    k_out   <<<NROWS / 16, 256, 0, stream>>>(x, ind, cnewT, out,
                                             out + (size_t)NROWS * DIM);
}

// Round 3
// 900.890 us; speedup vs baseline: 3.8526x; 1.3160x over previous
//
#include <hip/hip_runtime.h>
#include <math.h>

#define NROWS 131072
#define DIM   64
#define KCENT 1024
#define DECAY 0.99f
#define EPS_  1e-5f
#define CSTR  80   // centT row stride in floats: 64 dims + c_sq + pad -> 320B (64B-aligned)

// ---------------- ws layout (float elements) ----------------
// csum   [K*D]   @ 0        (written densely by k_segsum)
// cnt    [K]     @ 65536    (int, zeroed)
// cs     [K]     @ 66560
// cnewT  [K*D]   @ 67584    ([K][D] codebook for coalesced gather)
// ind    [N]     @ 133120   (int)
// perm   [N]     @ 264192   (int)
// start  [K]     @ 395264   (int)
// cursor [K]     @ 396288   (int)
// centT  [K*80]  @ 397312   ([K][80]: 64 dims + ||c||^2 @ [64])
// total ~1.87 MB

// ---------- K1: transpose centroids to [K][80] rows + ||c_k||^2 ----------
__global__ void k_ctrans(const float* __restrict__ cent, float* __restrict__ centT) {
    int k = blockIdx.x * 256 + threadIdx.x;   // 0..1023
    float sq = 0.f;
#pragma unroll
    for (int d0 = 0; d0 < DIM; d0 += 4) {
        float4 v;
        v.x = cent[(d0 + 0) * KCENT + k];     // coalesced across lanes
        v.y = cent[(d0 + 1) * KCENT + k];
        v.z = cent[(d0 + 2) * KCENT + k];
        v.w = cent[(d0 + 3) * KCENT + k];
        sq = fmaf(v.x, v.x, fmaf(v.y, v.y, fmaf(v.z, v.z, fmaf(v.w, v.w, sq))));
        ((float4*)(centT + (size_t)k * CSTR))[d0 >> 2] = v;
    }
    centT[(size_t)k * CSTR + 64] = sq;
}

// ---------- K2: nearest-centroid assignment ----------
// Centroid row address is wave-uniform (loop index only) -> scalar s_load path
// (or L1-broadcast vector loads); no LDS staging at all.
__global__ __launch_bounds__(256) void k_assign(
    const float* __restrict__ x, const float* __restrict__ centT,
    int* __restrict__ ind, int* __restrict__ cnt) {
    __shared__ int hist[KCENT];
#pragma unroll
    for (int i = 0; i < KCENT / 256; ++i) hist[threadIdx.x + i * 256] = 0;
    __syncthreads();

    const int n = blockIdx.x * 256 + threadIdx.x;
    float4 xv[16];
    const float4* xr = (const float4*)(x + (size_t)n * DIM);
#pragma unroll
    for (int i = 0; i < 16; ++i) xv[i] = xr[i];

    float best = 3.402823466e38f;
    int   bi   = 0;

    for (int k = 0; k < KCENT; ++k) {
        const float*  crow = centT + k * CSTR;   // uniform address
        const float4* cv   = (const float4*)crow;
        float4 a = make_float4(0.f, 0.f, 0.f, 0.f);
#pragma unroll
        for (int i = 0; i < 16; ++i) {
            float4 c = cv[i];
            a.x = fmaf(xv[i].x, c.x, a.x);
            a.y = fmaf(xv[i].y, c.y, a.y);
            a.z = fmaf(xv[i].z, c.z, a.z);
            a.w = fmaf(xv[i].w, c.w, a.w);
        }
        float dot  = (a.x + a.y) + (a.z + a.w);
        float dist = crow[64] - 2.0f * dot;      // x_sq omitted: row-constant
        if (dist < best) { best = dist; bi = k; }  // strict < == first-min tiebreak
    }

    ind[n] = bi;
    atomicAdd(&hist[bi], 1);          // LDS atomic
    __syncthreads();
#pragma unroll
    for (int i = 0; i < KCENT / 256; ++i) {
        int b = threadIdx.x + i * 256;
        int v = hist[b];
        if (v) atomicAdd(&cnt[b], v); // ~226 global atomics / block
    }
}

// ---------- K3: EMA stats + Laplace cs + exclusive prefix sum ----------
__global__ void k_scan(const float* __restrict__ cluster_size,
                       const int* __restrict__ cnt,
                       float* __restrict__ cs,
                       int* __restrict__ start, int* __restrict__ cursor) {
    __shared__ int   sa[KCENT], sb[KCENT];
    __shared__ float rf[KCENT];
    const int t = threadIdx.x;
    const int c = cnt[t];

    float cls = DECAY * cluster_size[t] + (1.0f - DECAY) * (float)c;
    rf[t] = cls;
    __syncthreads();
    for (int off = KCENT / 2; off > 0; off >>= 1) {
        if (t < off) rf[t] += rf[t + off];
        __syncthreads();
    }
    float ntot = rf[0];
    cs[t] = (cls + EPS_) / (ntot + KCENT * EPS_) * ntot;

    sa[t] = c;
    __syncthreads();
    int* pin = sa; int* pout = sb;
    for (int off = 1; off < KCENT; off <<= 1) {
        pout[t] = pin[t] + ((t >= off) ? pin[t - off] : 0);
        __syncthreads();
        int* tmp = pin; pin = pout; pout = tmp;
    }
    int excl = pin[t] - c;
    start[t]  = excl;
    cursor[t] = excl;
}

// ---------- K4: scatter rows into cluster-sorted order ----------
__global__ __launch_bounds__(256) void k_scatter(
    const int* __restrict__ ind, int* __restrict__ cursor,
    int* __restrict__ perm) {
    int n = blockIdx.x * 256 + threadIdx.x;
    int bi = ind[n];
    int pos = atomicAdd(&cursor[bi], 1);   // 131K atomics on 1024 addrs
    perm[pos] = n;
}

// ---------- K5: dense per-cluster segment sum (no atomics) ----------
__global__ __launch_bounds__(256) void k_segsum(
    const float* __restrict__ x, const int* __restrict__ perm,
    const int* __restrict__ start, const int* __restrict__ cnt,
    float* __restrict__ csum) {
    const int k = blockIdx.x;
    const int w = threadIdx.x >> 6;    // wave 0..3
    const int d = threadIdx.x & 63;    // dim
    const int s = start[k];
    const int c = cnt[k];

    float acc = 0.f;
    int r = w;
    for (; r + 4 < c; r += 8) {        // 2 rows in flight per iter
        int row0 = perm[s + r];
        int row1 = perm[s + r + 4];
        acc += x[(size_t)row0 * DIM + d];
        acc += x[(size_t)row1 * DIM + d];
    }
    for (; r < c; r += 4)
        acc += x[(size_t)perm[s + r] * DIM + d];

    __shared__ float red[256];
    red[threadIdx.x] = acc;
    __syncthreads();
    if (w == 0)
        csum[(size_t)k * DIM + d] = red[d] + red[64 + d] + red[128 + d] + red[192 + d];
}

// ---------- K6: centroids_new, stored transposed [K][D] ----------
__global__ void k_newcent(const float* __restrict__ avg,
                          const float* __restrict__ csum,
                          const float* __restrict__ cs,
                          float* __restrict__ cnewT) {
    int idx = blockIdx.x * blockDim.x + threadIdx.x;  // = k*64 + d
    int k = idx >> 6, d = idx & 63;
    float v = DECAY * avg[d * KCENT + k] + (1.0f - DECAY) * csum[idx];
    cnewT[idx] = v / cs[k];
}

// ---------- K7: gather quantized rows + MSE loss (256 blocks, 256 atomics) ----------
__global__ __launch_bounds__(256) void k_out(
    const float* __restrict__ x, const int* __restrict__ ind,
    const float* __restrict__ cnewT, float* __restrict__ out,
    float* __restrict__ loss) {
    const int tid = threadIdx.x;
    const int l16 = tid & 15;
    float p = 0.f;

    for (int g = blockIdx.x; g < NROWS / 16; g += 256) {
        int row = g * 16 + (tid >> 4);  // 16 rows per iter, 16 lanes/row
        int k = ind[row];
        float4 q  = ((const float4*)(cnewT + (size_t)k * DIM))[l16];
        float4 xw = ((const float4*)(x + (size_t)row * DIM))[l16];
        ((float4*)(out + (size_t)row * DIM))[l16] = q;
        float dx = xw.x - q.x, dy = xw.y - q.y, dz = xw.z - q.z, dw = xw.w - q.w;
        p += dx * dx + dy * dy + dz * dz + dw * dw;
    }

    __shared__ float red[256];
    red[tid] = p;
    __syncthreads();
    for (int off = 128; off > 0; off >>= 1) {
        if (tid < off) red[tid] += red[tid + off];
        __syncthreads();
    }
    if (tid == 0)
        atomicAdd(loss, red[0] * (1.0f / ((float)NROWS * (float)DIM)));
}

extern "C" void kernel_launch(void* const* d_in, const int* in_sizes, int n_in,
                              void* d_out, int out_size, void* d_ws, size_t ws_size,
                              hipStream_t stream) {
    const float* x            = (const float*)d_in[0];
    const float* cent         = (const float*)d_in[1];
    const float* cluster_size = (const float*)d_in[2];
    const float* avg          = (const float*)d_in[3];
    float* out = (float*)d_out;

    float* ws     = (float*)d_ws;
    float* csum   = ws;                    // K*D
    int*   cnt    = (int*)(ws + 65536);    // K
    float* cs     = ws + 66560;            // K
    float* cnewT  = ws + 67584;            // K*D
    int*   ind    = (int*)(ws + 133120);   // N
    int*   perm   = (int*)(ws + 264192);   // N
    int*   start  = (int*)(ws + 395264);   // K
    int*   cursor = (int*)(ws + 396288);   // K
    float* centT  = ws + 397312;           // K*80

    hipMemsetAsync(cnt, 0, KCENT * sizeof(int), stream);
    hipMemsetAsync(out + (size_t)NROWS * DIM, 0, sizeof(float), stream);  // loss slot

    k_ctrans<<<KCENT / 256, 256, 0, stream>>>(cent, centT);
    k_assign<<<NROWS / 256, 256, 0, stream>>>(x, centT, ind, cnt);
    k_scan  <<<1, KCENT, 0, stream>>>(cluster_size, cnt, cs, start, cursor);
    k_scatter<<<NROWS / 256, 256, 0, stream>>>(ind, cursor, perm);
    k_segsum<<<KCENT, 256, 0, stream>>>(x, perm, start, cnt, csum);
    k_newcent<<<(KCENT * DIM) / 256, 256, 0, stream>>>(avg, csum, cs, cnewT);
    k_out   <<<256, 256, 0, stream>>>(x, ind, cnewT, out,
                                      out + (size_t)NROWS * DIM);
}